// Round 9
// baseline (304.479 us; speedup 1.0000x reference)
//
#include <hip/hip_runtime.h>
#include <hip/hip_bf16.h>

#define N_ENT 100000
#define N_USR 30000
#define N_TOTN 130000
#define N_RELC 32
#define DIM 64
#define NEDGE 500000
#define INTER 500000
#define SLOPE 0.01f
#define FILL_NB 1954  // ceil(500000/256)
#define ATT_NB 1024   // att blocks inside fused k_l1
#define RSTR 64       // fixed CSR row stride (max degree; Poisson(16.7) tail ~1e-16)
#define ZB16 90016    // zero region float4 count: (130000*4 + 256 + 130000*4 + 100000*4)/16
#define ZERO_NB 352   // ceil(90016/256)

typedef unsigned char u8;
typedef unsigned long long u64;

__device__ __forceinline__ float grp_sum16(float v){
  v += __shfl_xor(v, 8, 64);
  v += __shfl_xor(v, 4, 64);
  v += __shfl_xor(v, 2, 64);
  v += __shfl_xor(v, 1, 64);
  return v;
}

// fused: m_rel/b_rel precompute (17 blocks) + zero-init of cnt/counters/flags
__global__ void __launch_bounds__(256) k_prep(
    const float* __restrict__ rel, const float* __restrict__ Wk,
    const float* __restrict__ Wkb, float* __restrict__ m, float* __restrict__ b,
    float4* __restrict__ zbase){
  int bid = blockIdx.x;
  if (bid < 17){
    int idx = bid*256 + threadIdx.x;
    if (idx < N_RELC*128){
      int r = idx >> 7, j = idx & 127;
      float s = 0.f;
      for (int d = 0; d < DIM; ++d) s += rel[r*DIM+d] * Wk[d*128+j];
      m[idx] = s;
    } else if (idx < N_RELC*128 + N_RELC){
      int r = idx - N_RELC*128;
      float s = 0.f;
      for (int d = 0; d < DIM; ++d) s += Wkb[d] * rel[r*DIM+d];
      b[r] = s;
    }
  } else {
    int i = (bid - 17)*256 + threadIdx.x;
    if (i < ZB16) zbase[i] = make_float4(0.f, 0.f, 0.f, 0.f);
  }
}

// flag-free full CSR build: every pair writes both directions (bump-alloc, int2 col|val)
__global__ void k_fillall(const int* __restrict__ a_row, const int* __restrict__ a_col,
                          const float* __restrict__ a_vals,
                          int* __restrict__ cnt, int2* __restrict__ csr){
  int i = blockIdx.x*256 + threadIdx.x;
  if (i >= INTER) return;
  int it = a_row[i];            // < N_ENT
  int uc = a_col[i];            // >= N_ENT
  int p = atomicAdd(&cnt[it], 1);
  if (p < RSTR) csr[((size_t)it << 6) + p] = make_int2(uc, __float_as_int(a_vals[i]));
  int q = atomicAdd(&cnt[uc], 1);
  if (q < RSTR) csr[((size_t)uc << 6) + q] = make_int2(it, __float_as_int(a_vals[i + INTER]));
}

// frontier construction from the 3072 output rows' CSR entries:
// dedup via atomicExch flags, ballot-aggregated list appends.
// blocks 0..767: one wave per output row walks its CSR row.
// block 768: appends the output rows themselves to list_s1.
__global__ void __launch_bounds__(256) k_mark2(
    const int* __restrict__ user_ids, const int* __restrict__ item_ids,
    const int* __restrict__ cnt, const int2* __restrict__ csr,
    int* __restrict__ flag_s1, int* __restrict__ flag_g,
    int* __restrict__ list_s1, int* __restrict__ list_gate,
    int* __restrict__ counters){
  int lane = threadIdx.x & 63;
  u64 lmask = (1ull << lane) - 1;
  if (blockIdx.x < 768){
    int w = (blockIdx.x*256 + threadIdx.x) >> 6;      // 0..3071
    int id = (w < 1024) ? user_ids[w] : item_ids[w - 1024];
    int deg = cnt[id]; if (deg > RSTR) deg = RSTR;
    int c = -1;
    if (lane < deg) c = csr[((size_t)id << 6) + lane].x;
    bool ns1 = false, ng = false;
    if (c >= 0){
      ns1 = (atomicExch(&flag_s1[c], 1) == 0);
      if (c < N_ENT) ng = (atomicExch(&flag_g[c], 1) == 0);
    }
    u64 m1 = __ballot(ns1);
    if (m1){
      int leader = __ffsll(m1) - 1;
      int base = 0;
      if (lane == leader) base = atomicAdd(&counters[1], __popcll(m1));
      base = __shfl(base, leader, 64);
      if (ns1) list_s1[base + __popcll(m1 & lmask)] = c;
    }
    u64 m2 = __ballot(ng);
    if (m2){
      int leader = __ffsll(m2) - 1;
      int base = 0;
      if (lane == leader) base = atomicAdd(&counters[0], __popcll(m2));
      base = __shfl(base, leader, 64);
      if (ng) list_gate[base + __popcll(m2 & lmask)] = c;
    }
  } else {
    for (int i = threadIdx.x; i < 3072; i += 256){
      int id = (i < 1024) ? user_ids[i] : item_ids[i - 1024];
      bool ns1 = (atomicExch(&flag_s1[id], 1) == 0);
      u64 m1 = __ballot(ns1);
      if (m1){
        int leader = __ffsll(m1) - 1;
        int base = 0;
        if (lane == leader) base = atomicAdd(&counters[1], __popcll(m1));
        base = __shfl(base, leader, 64);
        if (ns1) list_s1[base + __popcll(m1 & lmask)] = id;
      }
    }
  }
}

// fused layer-1: blocks < ATT_NB run attention (binary-search bounds, chunked
// cooperative edge preload, single-pass softmax w/o max shift — logits O(1)),
// remaining blocks run restricted fixed-stride SpMM (src = all_embed).
__global__ void __launch_bounds__(256) k_l1(const float4* __restrict__ ent4,
    const float4* __restrict__ m4, const float* __restrict__ bvec,
    const int* __restrict__ h_list, const int* __restrict__ t_list,
    const int* __restrict__ r_list, const int* __restrict__ list_gate,
    const int* __restrict__ list_s1, const int* __restrict__ counters,
    float4* __restrict__ kg4, const int* __restrict__ cnt,
    const int2* __restrict__ csr,
    float4* __restrict__ collab4, float4* __restrict__ x2_4){
  if (blockIdx.x < ATT_NB){
    __shared__ float4 msh[N_RELC*32];
    __shared__ float bsh[N_RELC];
    for (int i = threadIdx.x; i < N_RELC*32; i += 256) msh[i] = m4[i];
    if (threadIdx.x < N_RELC) bsh[threadIdx.x] = bvec[threadIdx.x];
    __syncthreads();
    int n = counters[0];
    int sub = threadIdx.x & 15;
    int grp = (blockIdx.x*256 + threadIdx.x) >> 4;
    int ng = (ATT_NB*256) >> 4;
    for (int idx = grp; idx < n; idx += ng){
      int s = list_gate[idx];
      // binary search [beg,end) in sorted h_list
      int lo = 0, hi = NEDGE;
      while (lo < hi){ int mid = (lo + hi) >> 1; if (h_list[mid] < s) lo = mid + 1; else hi = mid; }
      int beg = lo;
      hi = NEDGE;
      while (lo < hi){ int mid = (lo + hi) >> 1; if (h_list[mid] <= s) lo = mid + 1; else hi = mid; }
      int end = lo;
      float4 h4 = ent4[(size_t)s*16 + sub];
      float l = 0.f;
      float4 acc = {0.f,0.f,0.f,0.f};
      for (int base = beg; base < end; base += 16){
        int mch = end - base; if (mch > 16) mch = 16;
        int tj = 0, rj = 0;
        if (sub < mch){ tj = t_list[base + sub]; rj = r_list[base + sub]; }
        #pragma unroll 4
        for (int j = 0; j < mch; ++j){
          int ti = __shfl(tj, j, 16);
          int r  = __shfl(rj, j, 16);
          float4 t4 = ent4[(size_t)ti*16 + sub];
          float4 mt = msh[r*32 + sub];
          float4 mh = msh[r*32 + 16 + sub];
          float v = t4.x*mt.x + t4.y*mt.y + t4.z*mt.z + t4.w*mt.w
                  + h4.x*mh.x + h4.y*mh.y + h4.z*mh.z + h4.w*mh.w;
          v = grp_sum16(v) + bsh[r];
          v = (v >= 0.f) ? v : SLOPE * v;
          float w = __expf(v);
          l += w;
          acc.x += w*t4.x; acc.y += w*t4.y; acc.z += w*t4.z; acc.w += w*t4.w;
        }
      }
      float inv = (end > beg) ? 1.f / l : 0.f;
      float4 o = {acc.x*inv, acc.y*inv, acc.z*inv, acc.w*inv};
      kg4[(size_t)s*16 + sub] = o;
    }
  } else {
    int n = counters[1];
    int sub = threadIdx.x & 15;
    int bid = blockIdx.x - ATT_NB;
    int nb = gridDim.x - ATT_NB;
    int grp = (bid*256 + threadIdx.x) >> 4;
    int ng = (nb*256) >> 4;
    for (int idx = grp; idx < n; idx += ng){
      int i = list_s1[idx];
      int deg = cnt[i]; if (deg > RSTR) deg = RSTR;
      size_t base0 = (size_t)i << 6;
      float4 acc = {0.f,0.f,0.f,0.f};
      for (int b = 0; b < deg; b += 16){
        int mch = deg - b; if (mch > 16) mch = 16;
        int2 e = make_int2(0, 0);
        if (sub < mch) e = csr[base0 + b + sub];
        #pragma unroll 4
        for (int j = 0; j < mch; ++j){
          int cj = __shfl(e.x, j, 16);
          float vj = __int_as_float(__shfl(e.y, j, 16));
          float4 sv = ent4[(size_t)cj*16 + sub];   // src = all_embed table
          acc.x += vj*sv.x; acc.y += vj*sv.y; acc.z += vj*sv.z; acc.w += vj*sv.w;
        }
      }
      if (i < N_ENT) collab4[(size_t)i*16 + sub] = acc;
      else x2_4[(size_t)i*16 + sub] = acc;
    }
  }
}

// gate over list rows: dual = g*kg + (1-g)*collab -> x2 rows < N_ENT
__global__ void __launch_bounds__(256) k_gate(const float* __restrict__ kg,
    const float* __restrict__ collab, const float* __restrict__ Wa,
    const float* __restrict__ Wb, float* __restrict__ x2dual,
    const int* __restrict__ list, const int* __restrict__ counters){
  int n = counters[0];
  int row0 = blockIdx.x * 64;
  if (row0 >= n) return;
  __shared__ float Xsh[64][129];
  __shared__ float Wsh[128][65];
  for (int i = threadIdx.x; i < 64*64; i += 256){
    int a = i >> 6, j = i & 63;
    Wsh[j][a] = Wa[i];
    Wsh[64 + j][a] = Wb[i];
  }
  for (int i = threadIdx.x; i < 64*128; i += 256){
    int r = i >> 7, c = i & 127;
    int idx = row0 + r;
    float v = 0.f;
    if (idx < n){
      int row = list[idx];
      v = (c < 64) ? kg[(size_t)row*64 + c] : collab[(size_t)row*64 + (c - 64)];
    }
    Xsh[r][c] = v;
  }
  __syncthreads();
  int ct = threadIdx.x & 15, rt = threadIdx.x >> 4;
  int r0 = rt * 4, c0 = ct * 4;
  float acc[4][4] = {};
  for (int k = 0; k < 128; ++k){
    float w0 = Wsh[k][c0], w1 = Wsh[k][c0+1], w2 = Wsh[k][c0+2], w3 = Wsh[k][c0+3];
    #pragma unroll
    for (int i = 0; i < 4; ++i){
      float x = Xsh[r0+i][k];
      acc[i][0] += x*w0; acc[i][1] += x*w1; acc[i][2] += x*w2; acc[i][3] += x*w3;
    }
  }
  #pragma unroll
  for (int i = 0; i < 4; ++i){
    int idx = row0 + r0 + i;
    if (idx < n){
      int row = list[idx];
      float4 o;
      #pragma unroll
      for (int j = 0; j < 4; ++j){
        int c = c0 + j;
        float g = 1.f / (1.f + __expf(-acc[i][j]));
        float kv = Xsh[r0+i][c];
        float cv = Xsh[r0+i][64 + c];
        (&o.x)[j] = g*kv + (1.f - g)*cv;
      }
      *(float4*)&x2dual[(size_t)row*64 + c0] = o;
    }
  }
}

// fused spmm-2 + gather: one 64-lane wave per output row, lane = dim.
__global__ void __launch_bounds__(256) k_spmm2g(const int* __restrict__ cnt,
    const int2* __restrict__ csr, const float* __restrict__ x2,
    const float* __restrict__ all_embed, const float* __restrict__ collab1,
    const int* __restrict__ user_ids, const int* __restrict__ item_ids,
    float* __restrict__ user_e, float* __restrict__ item_e){
  int lane = threadIdx.x & 63;
  int g = (blockIdx.x*256 + threadIdx.x) >> 6;
  if (g >= 3072) return;
  int id;
  float b1;
  if (g < 1024){
    id = user_ids[g];                            // >= N_ENT
    b1 = x2[(size_t)id*64 + lane];               // users1 lives in x2
  } else {
    id = item_ids[g - 1024];
    b1 = collab1[(size_t)id*64 + lane];
  }
  float acc = all_embed[(size_t)id*64 + lane] + b1;
  int deg = cnt[id]; if (deg > RSTR) deg = RSTR;
  size_t base0 = (size_t)id << 6;
  int2 e = make_int2(0, 0);
  if (lane < deg) e = csr[base0 + lane];
  for (int j = 0; j < deg; ++j){
    int cj = __shfl(e.x, j, 64);
    float vj = __int_as_float(__shfl(e.y, j, 64));
    acc += vj * x2[(size_t)cj*64 + lane];
  }
  if (g < 1024) user_e[(size_t)g*64 + lane] = acc;
  else item_e[(size_t)(g - 1024)*64 + lane] = acc;
}

// out[1024][2048] = user_e @ item_e^T, 32x32 tiles, 2x2 micro-tile, K=64
__global__ void __launch_bounds__(256) k_out(const float* __restrict__ ue,
    const float* __restrict__ ie, float* __restrict__ out){
  __shared__ float ash[32][65];
  __shared__ float bsh[32][65];
  int row0 = blockIdx.y * 32, col0 = blockIdx.x * 32;
  for (int i = threadIdx.x; i < 32*64; i += 256){
    int r = i >> 6, c = i & 63;
    ash[r][c] = ue[(size_t)(row0 + r)*DIM + c];
    bsh[r][c] = ie[(size_t)(col0 + r)*DIM + c];
  }
  __syncthreads();
  int tx = threadIdx.x & 15, ty = threadIdx.x >> 4;
  int r0 = ty*2, c0 = tx*2;
  float a00=0.f, a01=0.f, a10=0.f, a11=0.f;
  #pragma unroll
  for (int k = 0; k < 64; ++k){
    float x0 = ash[r0][k], x1 = ash[r0+1][k];
    float y0 = bsh[c0][k], y1 = bsh[c0+1][k];
    a00 += x0*y0; a01 += x0*y1; a10 += x1*y0; a11 += x1*y1;
  }
  float2 o0 = {a00, a01}, o1 = {a10, a11};
  *(float2*)&out[(size_t)(row0 + r0)*2048 + col0 + c0] = o0;
  *(float2*)&out[(size_t)(row0 + r0 + 1)*2048 + col0 + c0] = o1;
}

extern "C" void kernel_launch(void* const* d_in, const int* in_sizes, int n_in,
                              void* d_out, int out_size, void* d_ws, size_t ws_size,
                              hipStream_t stream){
  const float* all_embed = (const float*)d_in[0];
  const float* rel_embed = (const float*)d_in[1];
  const float* Wk_w      = (const float*)d_in[2];
  const float* Wk_b      = (const float*)d_in[3];
  const float* Wa_w      = (const float*)d_in[4];
  const float* Wb_w      = (const float*)d_in[5];
  const float* a_vals    = (const float*)d_in[6];
  const int* user_ids   = (const int*)d_in[7];
  const int* item_ids   = (const int*)d_in[8];
  const int* h_list     = (const int*)d_in[9];
  const int* t_list     = (const int*)d_in[10];
  const int* r_list     = (const int*)d_in[11];
  const int* a_row      = (const int*)d_in[12];
  const int* a_col      = (const int*)d_in[13];
  float* out = (float*)d_out;

  char* p = (char*)d_ws;
  auto alloc = [&](size_t bytes)->void*{
    void* r = (void*)p;
    p += (bytes + 255) & ~(size_t)255;
    return r;
  };
  float* m_rel   = (float*)alloc((size_t)N_RELC*128*4);
  float* b_rel   = (float*)alloc((size_t)N_RELC*4);
  // zero region: cnt | counters | flag_s1 | flag_g  (ZB16 float4s, zeroed by k_prep)
  char*  zbase    = (char*)alloc((size_t)ZB16*16);
  int*   cnt      = (int*)zbase;
  int*   counters = (int*)(zbase + (size_t)N_TOTN*4);   // [0]=gate n, [1]=s1 n
  int*   flag_s1  = (int*)(zbase + (size_t)N_TOTN*4 + 256);
  int*   flag_g   = flag_s1 + N_TOTN;
  int2*  csr     = (int2*) alloc((size_t)N_TOTN*RSTR*8);
  int*   list_gate = (int*)alloc((size_t)N_ENT*4);
  int*   list_s1   = (int*)alloc((size_t)N_TOTN*4);
  float* kg1     = (float*)alloc((size_t)N_ENT*DIM*4);
  float* collab1 = (float*)alloc((size_t)N_ENT*DIM*4);
  float* x2      = (float*)alloc((size_t)N_TOTN*DIM*4);  // [dual ; users1]
  float* user_e  = (float*)alloc((size_t)1024*DIM*4);
  float* item_e  = (float*)alloc((size_t)2048*DIM*4);

  k_prep<<<17 + ZERO_NB, 256, 0, stream>>>(rel_embed, Wk_w, Wk_b, m_rel, b_rel,
      (float4*)zbase);
  k_fillall<<<FILL_NB, 256, 0, stream>>>(a_row, a_col, a_vals, cnt, csr);
  k_mark2<<<769, 256, 0, stream>>>(user_ids, item_ids, cnt, csr,
      flag_s1, flag_g, list_s1, list_gate, counters);
  k_l1<<<ATT_NB + 2048, 256, 0, stream>>>((const float4*)all_embed,
      (const float4*)m_rel, b_rel, h_list, t_list, r_list, list_gate, list_s1,
      counters, (float4*)kg1, cnt, csr, (float4*)collab1, (float4*)x2);
  k_gate<<<(N_ENT + 63)/64, 256, 0, stream>>>(kg1, collab1, Wa_w, Wb_w, x2,
      list_gate, counters);
  k_spmm2g<<<768, 256, 0, stream>>>(cnt, csr, x2, all_embed, collab1,
      user_ids, item_ids, user_e, item_e);
  dim3 grid_out(2048/32, 1024/32);
  k_out<<<grid_out, 256, 0, stream>>>(user_e, item_e, out);
}

// Round 10
// 208.404 us; speedup vs baseline: 1.4610x; 1.4610x over previous
//
#include <hip/hip_runtime.h>
#include <hip/hip_bf16.h>

#define N_ENT 100000
#define N_USR 30000
#define N_TOTN 130000
#define N_RELC 32
#define DIM 64
#define NEDGE 500000
#define INTER 500000
#define SLOPE 0.01f
#define CPT_NB 127    // compaction blocks: 127*1024 = 130048 >= 130000
#define FILL_NB 1954  // ceil(500000/256)
#define ATT_NB 1024   // att blocks inside fused k_l1
#define RSTR 64       // fixed CSR row stride (max degree; Poisson(16.7) tail ~1e-16)

typedef unsigned char u8;
typedef unsigned long long u64;

__device__ __forceinline__ float grp_sum16(float v){
  v += __shfl_xor(v, 8, 64);
  v += __shfl_xor(v, 4, 64);
  v += __shfl_xor(v, 2, 64);
  v += __shfl_xor(v, 1, 64);
  return v;
}

// fused: m_rel/b_rel precompute + r2 output-row flags (29 blocks)
__global__ void __launch_bounds__(256) k_prep(
    const float* __restrict__ rel, const float* __restrict__ Wk,
    const float* __restrict__ Wkb, float* __restrict__ m, float* __restrict__ b,
    const int* __restrict__ user_ids, const int* __restrict__ item_ids,
    u8* __restrict__ r2_item, u8* __restrict__ r2_user){
  int bid = blockIdx.x;
  if (bid < 17){
    int idx = bid*256 + threadIdx.x;
    if (idx < N_RELC*128){
      int r = idx >> 7, j = idx & 127;
      float s = 0.f;
      for (int d = 0; d < DIM; ++d) s += rel[r*DIM+d] * Wk[d*128+j];
      m[idx] = s;
    } else if (idx < N_RELC*128 + N_RELC){
      int r = idx - N_RELC*128;
      float s = 0.f;
      for (int d = 0; d < DIM; ++d) s += Wkb[d] * rel[r*DIM+d];
      b[r] = s;
    }
  } else {
    int i = (bid - 17)*256 + threadIdx.x;
    if (i < 1024) r2_user[user_ids[i] - N_ENT] = 1;
    else if (i < 3072) r2_item[item_ids[i - 1024]] = 1;
  }
}

// mark spmm-2 input columns using bipartite symmetry: pair k = (it, N_ENT+u)
__global__ void k_mark(const int* __restrict__ a_row, const int* __restrict__ a_col,
                       const u8* __restrict__ r2_item, const u8* __restrict__ r2_user,
                       u8* __restrict__ need_d, u8* __restrict__ need_u){
  int i = blockIdx.x*256 + threadIdx.x;
  if (i >= INTER) return;
  int it = a_row[i];            // < N_ENT
  int uu = a_col[i] - N_ENT;    // user index
  if (r2_item[it]) need_u[uu] = 1;
  if (r2_user[uu]) need_d[it] = 1;
}

// fused: list compaction (blocks < CPT_NB, block-aggregated atomics)
//      + fixed-stride CSR fill (remaining blocks; bump-alloc per row, int2 col|val)
__global__ void __launch_bounds__(256) k_buildfill(
    const int* __restrict__ a_row, const int* __restrict__ a_col,
    const float* __restrict__ a_vals,
    const u8* __restrict__ need_d, const u8* __restrict__ need_u,
    const u8* __restrict__ r2_item, const u8* __restrict__ r2_user,
    int* __restrict__ list_gate, int* __restrict__ list_s1,
    int* __restrict__ counters, int* __restrict__ cnt, int2* __restrict__ csr){
  if (blockIdx.x < CPT_NB){
    __shared__ u64 mg_sh[16], ms_sh[16];
    __shared__ int pre_g[16], pre_s[16];
    __shared__ int base_sh[2];
    int t = threadIdx.x;
    int wave = t >> 6, lane = t & 63;
    bool pg[4], ps[4];
    int ibase = blockIdx.x*1024;
    #pragma unroll
    for (int k = 0; k < 4; ++k){
      int i = ibase + k*256 + t;
      bool g = false, s = false;
      if (i < N_TOTN){
        if (i < N_ENT){ g = need_d[i] != 0; s = g || (r2_item[i] != 0); }
        else { int u = i - N_ENT; s = (need_u[u] != 0) || (r2_user[u] != 0); }
      }
      pg[k] = g; ps[k] = s;
      u64 mg = __ballot(g), ms = __ballot(s);
      if (lane == 0){ mg_sh[k*4 + wave] = mg; ms_sh[k*4 + wave] = ms; }
    }
    __syncthreads();
    if (t == 0){
      int sg = 0, ss = 0;
      for (int j = 0; j < 16; ++j){
        pre_g[j] = sg; sg += __popcll(mg_sh[j]);
        pre_s[j] = ss; ss += __popcll(ms_sh[j]);
      }
      base_sh[0] = sg ? atomicAdd(&counters[0], sg) : 0;
      base_sh[1] = ss ? atomicAdd(&counters[1], ss) : 0;
    }
    __syncthreads();
    int bg = base_sh[0], bs = base_sh[1];
    u64 lmask = (1ull << lane) - 1;
    #pragma unroll
    for (int k = 0; k < 4; ++k){
      int i = ibase + k*256 + t;
      if (pg[k]) list_gate[bg + pre_g[k*4+wave] + __popcll(mg_sh[k*4+wave] & lmask)] = i;
      if (ps[k]) list_s1 [bs + pre_s[k*4+wave] + __popcll(ms_sh[k*4+wave] & lmask)] = i;
    }
  } else {
    int i = (blockIdx.x - CPT_NB)*256 + threadIdx.x;
    if (i >= INTER) return;
    int it = a_row[i];
    int uc = a_col[i];
    int uu = uc - N_ENT;
    if (need_d[it] | r2_item[it]){
      int p = atomicAdd(&cnt[it], 1);
      if (p < RSTR) csr[((size_t)it << 6) + p] = make_int2(uc, __float_as_int(a_vals[i]));
    }
    if (need_u[uu] | r2_user[uu]){
      int p = atomicAdd(&cnt[uc], 1);
      if (p < RSTR) csr[((size_t)uc << 6) + p] = make_int2(it, __float_as_int(a_vals[i + INTER]));
    }
  }
}

// fused layer-1: blocks < ATT_NB run attention (binary-search bounds, chunked
// cooperative edge preload, single-pass softmax w/o max shift — logits O(1)),
// remaining blocks run restricted fixed-stride SpMM (src = all_embed).
__global__ void __launch_bounds__(256) k_l1(const float4* __restrict__ ent4,
    const float4* __restrict__ m4, const float* __restrict__ bvec,
    const int* __restrict__ h_list, const int* __restrict__ t_list,
    const int* __restrict__ r_list, const int* __restrict__ list_gate,
    const int* __restrict__ list_s1, const int* __restrict__ counters,
    float4* __restrict__ kg4, const int* __restrict__ cnt,
    const int2* __restrict__ csr,
    float4* __restrict__ collab4, float4* __restrict__ x2_4){
  if (blockIdx.x < ATT_NB){
    __shared__ float4 msh[N_RELC*32];
    __shared__ float bsh[N_RELC];
    for (int i = threadIdx.x; i < N_RELC*32; i += 256) msh[i] = m4[i];
    if (threadIdx.x < N_RELC) bsh[threadIdx.x] = bvec[threadIdx.x];
    __syncthreads();
    int n = counters[0];
    int sub = threadIdx.x & 15;
    int grp = (blockIdx.x*256 + threadIdx.x) >> 4;
    int ng = (ATT_NB*256) >> 4;
    for (int idx = grp; idx < n; idx += ng){
      int s = list_gate[idx];
      // binary search [beg,end) in sorted h_list
      int lo = 0, hi = NEDGE;
      while (lo < hi){ int mid = (lo + hi) >> 1; if (h_list[mid] < s) lo = mid + 1; else hi = mid; }
      int beg = lo;
      hi = NEDGE;
      while (lo < hi){ int mid = (lo + hi) >> 1; if (h_list[mid] <= s) lo = mid + 1; else hi = mid; }
      int end = lo;
      float4 h4 = ent4[(size_t)s*16 + sub];
      float l = 0.f;
      float4 acc = {0.f,0.f,0.f,0.f};
      for (int base = beg; base < end; base += 16){
        int mch = end - base; if (mch > 16) mch = 16;
        int tj = 0, rj = 0;
        if (sub < mch){ tj = t_list[base + sub]; rj = r_list[base + sub]; }
        #pragma unroll 4
        for (int j = 0; j < mch; ++j){
          int ti = __shfl(tj, j, 16);
          int r  = __shfl(rj, j, 16);
          float4 t4 = ent4[(size_t)ti*16 + sub];
          float4 mt = msh[r*32 + sub];
          float4 mh = msh[r*32 + 16 + sub];
          float v = t4.x*mt.x + t4.y*mt.y + t4.z*mt.z + t4.w*mt.w
                  + h4.x*mh.x + h4.y*mh.y + h4.z*mh.z + h4.w*mh.w;
          v = grp_sum16(v) + bsh[r];
          v = (v >= 0.f) ? v : SLOPE * v;
          float w = __expf(v);
          l += w;
          acc.x += w*t4.x; acc.y += w*t4.y; acc.z += w*t4.z; acc.w += w*t4.w;
        }
      }
      float inv = (end > beg) ? 1.f / l : 0.f;
      float4 o = {acc.x*inv, acc.y*inv, acc.z*inv, acc.w*inv};
      kg4[(size_t)s*16 + sub] = o;
    }
  } else {
    int n = counters[1];
    int sub = threadIdx.x & 15;
    int bid = blockIdx.x - ATT_NB;
    int nb = gridDim.x - ATT_NB;
    int grp = (bid*256 + threadIdx.x) >> 4;
    int ng = (nb*256) >> 4;
    for (int idx = grp; idx < n; idx += ng){
      int i = list_s1[idx];
      int deg = cnt[i]; if (deg > RSTR) deg = RSTR;
      size_t base0 = (size_t)i << 6;
      float4 acc = {0.f,0.f,0.f,0.f};
      for (int b = 0; b < deg; b += 16){
        int mch = deg - b; if (mch > 16) mch = 16;
        int2 e = make_int2(0, 0);
        if (sub < mch) e = csr[base0 + b + sub];
        #pragma unroll 4
        for (int j = 0; j < mch; ++j){
          int cj = __shfl(e.x, j, 16);
          float vj = __int_as_float(__shfl(e.y, j, 16));
          float4 sv = ent4[(size_t)cj*16 + sub];   // src = all_embed table
          acc.x += vj*sv.x; acc.y += vj*sv.y; acc.z += vj*sv.z; acc.w += vj*sv.w;
        }
      }
      if (i < N_ENT) collab4[(size_t)i*16 + sub] = acc;
      else x2_4[(size_t)i*16 + sub] = acc;
    }
  }
}

// gate over list rows: dual = g*kg + (1-g)*collab -> x2 rows < N_ENT
__global__ void __launch_bounds__(256) k_gate(const float* __restrict__ kg,
    const float* __restrict__ collab, const float* __restrict__ Wa,
    const float* __restrict__ Wb, float* __restrict__ x2dual,
    const int* __restrict__ list, const int* __restrict__ counters){
  int n = counters[0];
  int row0 = blockIdx.x * 64;
  if (row0 >= n) return;
  __shared__ float Xsh[64][129];
  __shared__ float Wsh[128][65];
  for (int i = threadIdx.x; i < 64*64; i += 256){
    int a = i >> 6, j = i & 63;
    Wsh[j][a] = Wa[i];
    Wsh[64 + j][a] = Wb[i];
  }
  for (int i = threadIdx.x; i < 64*128; i += 256){
    int r = i >> 7, c = i & 127;
    int idx = row0 + r;
    float v = 0.f;
    if (idx < n){
      int row = list[idx];
      v = (c < 64) ? kg[(size_t)row*64 + c] : collab[(size_t)row*64 + (c - 64)];
    }
    Xsh[r][c] = v;
  }
  __syncthreads();
  int ct = threadIdx.x & 15, rt = threadIdx.x >> 4;
  int r0 = rt * 4, c0 = ct * 4;
  float acc[4][4] = {};
  for (int k = 0; k < 128; ++k){
    float w0 = Wsh[k][c0], w1 = Wsh[k][c0+1], w2 = Wsh[k][c0+2], w3 = Wsh[k][c0+3];
    #pragma unroll
    for (int i = 0; i < 4; ++i){
      float x = Xsh[r0+i][k];
      acc[i][0] += x*w0; acc[i][1] += x*w1; acc[i][2] += x*w2; acc[i][3] += x*w3;
    }
  }
  #pragma unroll
  for (int i = 0; i < 4; ++i){
    int idx = row0 + r0 + i;
    if (idx < n){
      int row = list[idx];
      float4 o;
      #pragma unroll
      for (int j = 0; j < 4; ++j){
        int c = c0 + j;
        float g = 1.f / (1.f + __expf(-acc[i][j]));
        float kv = Xsh[r0+i][c];
        float cv = Xsh[r0+i][64 + c];
        (&o.x)[j] = g*kv + (1.f - g)*cv;
      }
      *(float4*)&x2dual[(size_t)row*64 + c0] = o;
    }
  }
}

// fused spmm-2 + gather: one 64-lane wave per output row, lane = dim.
__global__ void __launch_bounds__(256) k_spmm2g(const int* __restrict__ cnt,
    const int2* __restrict__ csr, const float* __restrict__ x2,
    const float* __restrict__ all_embed, const float* __restrict__ collab1,
    const int* __restrict__ user_ids, const int* __restrict__ item_ids,
    float* __restrict__ user_e, float* __restrict__ item_e){
  int lane = threadIdx.x & 63;
  int g = (blockIdx.x*256 + threadIdx.x) >> 6;
  if (g >= 3072) return;
  int id;
  float b1;
  if (g < 1024){
    id = user_ids[g];                            // >= N_ENT
    b1 = x2[(size_t)id*64 + lane];               // users1 lives in x2
  } else {
    id = item_ids[g - 1024];
    b1 = collab1[(size_t)id*64 + lane];
  }
  float acc = all_embed[(size_t)id*64 + lane] + b1;
  int deg = cnt[id]; if (deg > RSTR) deg = RSTR;
  size_t base0 = (size_t)id << 6;
  int2 e = make_int2(0, 0);
  if (lane < deg) e = csr[base0 + lane];
  for (int j = 0; j < deg; ++j){
    int cj = __shfl(e.x, j, 64);
    float vj = __int_as_float(__shfl(e.y, j, 64));
    acc += vj * x2[(size_t)cj*64 + lane];
  }
  if (g < 1024) user_e[(size_t)g*64 + lane] = acc;
  else item_e[(size_t)(g - 1024)*64 + lane] = acc;
}

// out[1024][2048] = user_e @ item_e^T, 64x64 tiles, 4x4 micro-tile, K=64
__global__ void __launch_bounds__(256) k_out(const float* __restrict__ ue,
    const float* __restrict__ ie, float* __restrict__ out){
  __shared__ float ash[64][65];
  __shared__ float bsh[64][65];
  int row0 = blockIdx.y * 64, col0 = blockIdx.x * 64;
  for (int i = threadIdx.x; i < 64*64; i += 256){
    int r = i >> 6, c = i & 63;
    ash[r][c] = ue[(size_t)(row0 + r)*DIM + c];
    bsh[r][c] = ie[(size_t)(col0 + r)*DIM + c];
  }
  __syncthreads();
  int tx = threadIdx.x & 15, ty = threadIdx.x >> 4;
  int r0 = ty*4, c0 = tx*4;
  float acc[4][4] = {};
  #pragma unroll
  for (int k = 0; k < 64; ++k){
    float a0 = ash[r0][k], a1 = ash[r0+1][k], a2 = ash[r0+2][k], a3 = ash[r0+3][k];
    float b0 = bsh[c0][k], b1 = bsh[c0+1][k], b2 = bsh[c0+2][k], b3 = bsh[c0+3][k];
    acc[0][0] += a0*b0; acc[0][1] += a0*b1; acc[0][2] += a0*b2; acc[0][3] += a0*b3;
    acc[1][0] += a1*b0; acc[1][1] += a1*b1; acc[1][2] += a1*b2; acc[1][3] += a1*b3;
    acc[2][0] += a2*b0; acc[2][1] += a2*b1; acc[2][2] += a2*b2; acc[2][3] += a2*b3;
    acc[3][0] += a3*b0; acc[3][1] += a3*b1; acc[3][2] += a3*b2; acc[3][3] += a3*b3;
  }
  #pragma unroll
  for (int i = 0; i < 4; ++i){
    float4 o = {acc[i][0], acc[i][1], acc[i][2], acc[i][3]};
    *(float4*)&out[(size_t)(row0 + r0 + i)*2048 + col0 + c0] = o;
  }
}

extern "C" void kernel_launch(void* const* d_in, const int* in_sizes, int n_in,
                              void* d_out, int out_size, void* d_ws, size_t ws_size,
                              hipStream_t stream){
  const float* all_embed = (const float*)d_in[0];
  const float* rel_embed = (const float*)d_in[1];
  const float* Wk_w      = (const float*)d_in[2];
  const float* Wk_b      = (const float*)d_in[3];
  const float* Wa_w      = (const float*)d_in[4];
  const float* Wb_w      = (const float*)d_in[5];
  const float* a_vals    = (const float*)d_in[6];
  const int* user_ids   = (const int*)d_in[7];
  const int* item_ids   = (const int*)d_in[8];
  const int* h_list     = (const int*)d_in[9];
  const int* t_list     = (const int*)d_in[10];
  const int* r_list     = (const int*)d_in[11];
  const int* a_row      = (const int*)d_in[12];
  const int* a_col      = (const int*)d_in[13];
  float* out = (float*)d_out;

  char* p = (char*)d_ws;
  auto alloc = [&](size_t bytes)->void*{
    void* r = (void*)p;
    p += (bytes + 255) & ~(size_t)255;
    return r;
  };
  float* m_rel   = (float*)alloc((size_t)N_RELC*128*4);
  float* b_rel   = (float*)alloc((size_t)N_RELC*4);
  size_t zbytes = (size_t)N_TOTN*4 + 256 + (2*(size_t)N_ENT + 2*(size_t)N_USR);
  char*  zbase  = (char*)alloc(zbytes);
  int*   cnt      = (int*)zbase;
  int*   counters = (int*)(zbase + (size_t)N_TOTN*4);   // [0]=gate n, [1]=s1 n
  u8*    r2_item  = (u8*)(zbase + (size_t)N_TOTN*4 + 256);
  u8*    r2_user  = r2_item + N_ENT;
  u8*    need_d   = r2_user + N_USR;
  u8*    need_u   = need_d + N_ENT;
  int2*  csr     = (int2*) alloc((size_t)N_TOTN*RSTR*8);
  int*   list_gate = (int*)alloc((size_t)N_ENT*4);
  int*   list_s1   = (int*)alloc((size_t)N_TOTN*4);
  float* kg1     = (float*)alloc((size_t)N_ENT*DIM*4);
  float* collab1 = (float*)alloc((size_t)N_ENT*DIM*4);
  float* x2      = (float*)alloc((size_t)N_TOTN*DIM*4);  // [dual ; users1]
  float* user_e  = (float*)alloc((size_t)1024*DIM*4);
  float* item_e  = (float*)alloc((size_t)2048*DIM*4);

  hipMemsetAsync(zbase, 0, zbytes, stream);
  k_prep<<<29, 256, 0, stream>>>(rel_embed, Wk_w, Wk_b, m_rel, b_rel,
      user_ids, item_ids, r2_item, r2_user);
  k_mark<<<(INTER + 255)/256, 256, 0, stream>>>(a_row, a_col, r2_item, r2_user, need_d, need_u);
  k_buildfill<<<CPT_NB + FILL_NB, 256, 0, stream>>>(a_row, a_col, a_vals,
      need_d, need_u, r2_item, r2_user, list_gate, list_s1, counters, cnt, csr);
  // after k_buildfill: cnt[r] == deg(r) for needed rows, csr row r at [r*64, r*64+deg)

  k_l1<<<ATT_NB + 2048, 256, 0, stream>>>((const float4*)all_embed,
      (const float4*)m_rel, b_rel, h_list, t_list, r_list, list_gate, list_s1,
      counters, (float4*)kg1, cnt, csr, (float4*)collab1, (float4*)x2);
  k_gate<<<(N_ENT + 63)/64, 256, 0, stream>>>(kg1, collab1, Wa_w, Wb_w, x2,
      list_gate, counters);
  k_spmm2g<<<768, 256, 0, stream>>>(cnt, csr, x2, all_embed, collab1,
      user_ids, item_ids, user_e, item_e);
  dim3 grid_out(2048/64, 1024/64);
  k_out<<<grid_out, 256, 0, stream>>>(user_e, item_e, out);
}

// Round 12
// 201.263 us; speedup vs baseline: 1.5128x; 1.0355x over previous
//
#include <hip/hip_runtime.h>
#include <hip/hip_bf16.h>

#define N_ENT 100000
#define N_USR 30000
#define N_TOTN 130000
#define N_RELC 32
#define DIM 64
#define NEDGE 500000
#define INTER 500000
#define SLOPE 0.01f
#define CPT_NB 127     // compaction blocks: 127*1024 = 130048 >= 130000
#define FILL_NB 489    // ceil(125000/256) — 4 pairs per thread
#define MARK_NB 489
#define ATT_NB 1024    // att blocks inside fused k_l1
#define RSTR 64        // fixed CSR row stride (max degree; Poisson(16.7) tail ~1e-16)
#define KGOFF_NB 1954  // ceil((NEDGE+1)/256)

typedef unsigned char u8;
typedef unsigned long long u64;

__device__ __forceinline__ float grp_sum16(float v){
  v += __shfl_xor(v, 8, 64);
  v += __shfl_xor(v, 4, 64);
  v += __shfl_xor(v, 2, 64);
  v += __shfl_xor(v, 1, 64);
  return v;
}

// fused: m_rel/b_rel (17) + r2 flags (12) + kg_off boundary scan (1954).
// NOTE: zero-init of cnt/counters/flags is a SEPARATE prior hipMemsetAsync —
// folding it in here raced with the r2-flag writes (R11 failure).
__global__ void __launch_bounds__(256) k_prep(
    const float* __restrict__ rel, const float* __restrict__ Wk,
    const float* __restrict__ Wkb, float* __restrict__ m, float* __restrict__ b,
    const int* __restrict__ user_ids, const int* __restrict__ item_ids,
    u8* __restrict__ r2_item, u8* __restrict__ r2_user,
    const int* __restrict__ h_list, int* __restrict__ off){
  int bid = blockIdx.x;
  if (bid < 17){
    int idx = bid*256 + threadIdx.x;
    if (idx < N_RELC*128){
      int r = idx >> 7, j = idx & 127;
      float s = 0.f;
      for (int d = 0; d < DIM; ++d) s += rel[r*DIM+d] * Wk[d*128+j];
      m[idx] = s;
    } else if (idx < N_RELC*128 + N_RELC){
      int r = idx - N_RELC*128;
      float s = 0.f;
      for (int d = 0; d < DIM; ++d) s += Wkb[d] * rel[r*DIM+d];
      b[r] = s;
    }
  } else if (bid < 29){
    int i = (bid - 17)*256 + threadIdx.x;
    if (i < 1024) r2_user[user_ids[i] - N_ENT] = 1;
    else if (i < 3072) r2_item[item_ids[i - 1024]] = 1;
  } else {
    int e = (bid - 29)*256 + threadIdx.x;
    if (e <= NEDGE){
      int hc = (e < NEDGE) ? h_list[e] : N_ENT;
      int hp = (e == 0) ? -1 : h_list[e-1];
      for (int s = hp+1; s <= hc; ++s) off[s] = e;
    }
  }
}

// mark spmm-2 input columns (bipartite symmetry), 4 pairs per thread via int4
__global__ void k_mark(const int4* __restrict__ a_row4, const int4* __restrict__ a_col4,
                       const u8* __restrict__ r2_item, const u8* __restrict__ r2_user,
                       u8* __restrict__ need_d, u8* __restrict__ need_u){
  int i = blockIdx.x*256 + threadIdx.x;
  if (i >= INTER/4) return;
  int4 ar = a_row4[i];
  int4 ac = a_col4[i];
  #pragma unroll
  for (int k = 0; k < 4; ++k){
    int it = (&ar.x)[k];
    int uu = (&ac.x)[k] - N_ENT;
    if (r2_item[it]) need_u[uu] = 1;
    if (r2_user[uu]) need_d[it] = 1;
  }
}

// fused: list compaction (blocks < CPT_NB) + fixed-stride CSR fill (4 pairs/thread)
__global__ void __launch_bounds__(256) k_buildfill(
    const int* __restrict__ a_row, const int* __restrict__ a_col,
    const float* __restrict__ a_vals,
    const u8* __restrict__ need_d, const u8* __restrict__ need_u,
    const u8* __restrict__ r2_item, const u8* __restrict__ r2_user,
    int* __restrict__ list_gate, int* __restrict__ list_s1,
    int* __restrict__ counters, int* __restrict__ cnt, int2* __restrict__ csr){
  if (blockIdx.x < CPT_NB){
    __shared__ u64 mg_sh[16], ms_sh[16];
    __shared__ int pre_g[16], pre_s[16];
    __shared__ int base_sh[2];
    int t = threadIdx.x;
    int wave = t >> 6, lane = t & 63;
    bool pg[4], ps[4];
    int ibase = blockIdx.x*1024;
    #pragma unroll
    for (int k = 0; k < 4; ++k){
      int i = ibase + k*256 + t;
      bool g = false, s = false;
      if (i < N_TOTN){
        if (i < N_ENT){ g = need_d[i] != 0; s = g || (r2_item[i] != 0); }
        else { int u = i - N_ENT; s = (need_u[u] != 0) || (r2_user[u] != 0); }
      }
      pg[k] = g; ps[k] = s;
      u64 mg = __ballot(g), ms = __ballot(s);
      if (lane == 0){ mg_sh[k*4 + wave] = mg; ms_sh[k*4 + wave] = ms; }
    }
    __syncthreads();
    if (t == 0){
      int sg = 0, ss = 0;
      for (int j = 0; j < 16; ++j){
        pre_g[j] = sg; sg += __popcll(mg_sh[j]);
        pre_s[j] = ss; ss += __popcll(ms_sh[j]);
      }
      base_sh[0] = sg ? atomicAdd(&counters[0], sg) : 0;
      base_sh[1] = ss ? atomicAdd(&counters[1], ss) : 0;
    }
    __syncthreads();
    int bg = base_sh[0], bs = base_sh[1];
    u64 lmask = (1ull << lane) - 1;
    #pragma unroll
    for (int k = 0; k < 4; ++k){
      int i = ibase + k*256 + t;
      if (pg[k]) list_gate[bg + pre_g[k*4+wave] + __popcll(mg_sh[k*4+wave] & lmask)] = i;
      if (ps[k]) list_s1 [bs + pre_s[k*4+wave] + __popcll(ms_sh[k*4+wave] & lmask)] = i;
    }
  } else {
    int i = (blockIdx.x - CPT_NB)*256 + threadIdx.x;
    if (i >= INTER/4) return;
    int4 ar = ((const int4*)a_row)[i];
    int4 ac = ((const int4*)a_col)[i];
    float4 av0 = ((const float4*)a_vals)[i];
    float4 av1 = ((const float4*)(a_vals + INTER))[i];
    #pragma unroll
    for (int k = 0; k < 4; ++k){
      int it = (&ar.x)[k];
      int uc = (&ac.x)[k];
      int uu = uc - N_ENT;
      if (need_d[it] | r2_item[it]){
        int p = atomicAdd(&cnt[it], 1);
        if (p < RSTR) csr[((size_t)it << 6) + p] = make_int2(uc, __float_as_int((&av0.x)[k]));
      }
      if (need_u[uu] | r2_user[uu]){
        int p = atomicAdd(&cnt[uc], 1);
        if (p < RSTR) csr[((size_t)uc << 6) + p] = make_int2(it, __float_as_int((&av1.x)[k]));
      }
    }
  }
}

// fused layer-1: blocks < ATT_NB run attention (off[] bounds, chunked cooperative
// edge preload, single-pass softmax w/o max shift — logits O(1)), rest run SpMM.
__global__ void __launch_bounds__(256) k_l1(const float4* __restrict__ ent4,
    const float4* __restrict__ m4, const float* __restrict__ bvec,
    const int* __restrict__ off, const int* __restrict__ t_list,
    const int* __restrict__ r_list, const int* __restrict__ list_gate,
    const int* __restrict__ list_s1, const int* __restrict__ counters,
    float4* __restrict__ kg4, const int* __restrict__ cnt,
    const int2* __restrict__ csr,
    float4* __restrict__ collab4, float4* __restrict__ x2_4){
  if (blockIdx.x < ATT_NB){
    __shared__ float4 msh[N_RELC*32];
    __shared__ float bsh[N_RELC];
    for (int i = threadIdx.x; i < N_RELC*32; i += 256) msh[i] = m4[i];
    if (threadIdx.x < N_RELC) bsh[threadIdx.x] = bvec[threadIdx.x];
    __syncthreads();
    int n = counters[0];
    int sub = threadIdx.x & 15;
    int grp = (blockIdx.x*256 + threadIdx.x) >> 4;
    int ng = (ATT_NB*256) >> 4;
    for (int idx = grp; idx < n; idx += ng){
      int s = list_gate[idx];
      int beg = off[s], end = off[s+1];
      float4 h4 = ent4[(size_t)s*16 + sub];
      float l = 0.f;
      float4 acc = {0.f,0.f,0.f,0.f};
      for (int base = beg; base < end; base += 16){
        int mch = end - base; if (mch > 16) mch = 16;
        int tj = 0, rj = 0;
        if (sub < mch){ tj = t_list[base + sub]; rj = r_list[base + sub]; }
        #pragma unroll 4
        for (int j = 0; j < mch; ++j){
          int ti = __shfl(tj, j, 16);
          int r  = __shfl(rj, j, 16);
          float4 t4 = ent4[(size_t)ti*16 + sub];
          float4 mt = msh[r*32 + sub];
          float4 mh = msh[r*32 + 16 + sub];
          float v = t4.x*mt.x + t4.y*mt.y + t4.z*mt.z + t4.w*mt.w
                  + h4.x*mh.x + h4.y*mh.y + h4.z*mh.z + h4.w*mh.w;
          v = grp_sum16(v) + bsh[r];
          v = (v >= 0.f) ? v : SLOPE * v;
          float w = __expf(v);
          l += w;
          acc.x += w*t4.x; acc.y += w*t4.y; acc.z += w*t4.z; acc.w += w*t4.w;
        }
      }
      float inv = (end > beg) ? 1.f / l : 0.f;
      float4 o = {acc.x*inv, acc.y*inv, acc.z*inv, acc.w*inv};
      kg4[(size_t)s*16 + sub] = o;
    }
  } else {
    int n = counters[1];
    int sub = threadIdx.x & 15;
    int bid = blockIdx.x - ATT_NB;
    int nb = gridDim.x - ATT_NB;
    int grp = (bid*256 + threadIdx.x) >> 4;
    int ng = (nb*256) >> 4;
    for (int idx = grp; idx < n; idx += ng){
      int i = list_s1[idx];
      int deg = cnt[i]; if (deg > RSTR) deg = RSTR;
      size_t base0 = (size_t)i << 6;
      float4 acc = {0.f,0.f,0.f,0.f};
      for (int b = 0; b < deg; b += 16){
        int mch = deg - b; if (mch > 16) mch = 16;
        int2 e = make_int2(0, 0);
        if (sub < mch) e = csr[base0 + b + sub];
        #pragma unroll 4
        for (int j = 0; j < mch; ++j){
          int cj = __shfl(e.x, j, 16);
          float vj = __int_as_float(__shfl(e.y, j, 16));
          float4 sv = ent4[(size_t)cj*16 + sub];   // src = all_embed table
          acc.x += vj*sv.x; acc.y += vj*sv.y; acc.z += vj*sv.z; acc.w += vj*sv.w;
        }
      }
      if (i < N_ENT) collab4[(size_t)i*16 + sub] = acc;
      else x2_4[(size_t)i*16 + sub] = acc;
    }
  }
}

// gate over list rows (grid-stride tiles): dual = g*kg + (1-g)*collab -> x2
__global__ void __launch_bounds__(256) k_gate(const float* __restrict__ kg,
    const float* __restrict__ collab, const float* __restrict__ Wa,
    const float* __restrict__ Wb, float* __restrict__ x2dual,
    const int* __restrict__ list, const int* __restrict__ counters){
  int n = counters[0];
  __shared__ float Xsh[64][129];
  __shared__ float Wsh[128][65];
  for (int i = threadIdx.x; i < 64*64; i += 256){
    int a = i >> 6, j = i & 63;
    Wsh[j][a] = Wa[i];
    Wsh[64 + j][a] = Wb[i];
  }
  int ct = threadIdx.x & 15, rt = threadIdx.x >> 4;
  int r0 = rt * 4, c0 = ct * 4;
  for (int row0 = blockIdx.x*64; row0 < n; row0 += gridDim.x*64){
    __syncthreads();   // protect Xsh from previous tile's readers; orders Wsh load
    for (int i = threadIdx.x; i < 64*128; i += 256){
      int r = i >> 7, c = i & 127;
      int idx = row0 + r;
      float v = 0.f;
      if (idx < n){
        int row = list[idx];
        v = (c < 64) ? kg[(size_t)row*64 + c] : collab[(size_t)row*64 + (c - 64)];
      }
      Xsh[r][c] = v;
    }
    __syncthreads();
    float acc[4][4] = {};
    for (int k = 0; k < 128; ++k){
      float w0 = Wsh[k][c0], w1 = Wsh[k][c0+1], w2 = Wsh[k][c0+2], w3 = Wsh[k][c0+3];
      #pragma unroll
      for (int i = 0; i < 4; ++i){
        float x = Xsh[r0+i][k];
        acc[i][0] += x*w0; acc[i][1] += x*w1; acc[i][2] += x*w2; acc[i][3] += x*w3;
      }
    }
    #pragma unroll
    for (int i = 0; i < 4; ++i){
      int idx = row0 + r0 + i;
      if (idx < n){
        int row = list[idx];
        float4 o;
        #pragma unroll
        for (int j = 0; j < 4; ++j){
          int c = c0 + j;
          float g = 1.f / (1.f + __expf(-acc[i][j]));
          float kv = Xsh[r0+i][c];
          float cv = Xsh[r0+i][64 + c];
          (&o.x)[j] = g*kv + (1.f - g)*cv;
        }
        *(float4*)&x2dual[(size_t)row*64 + c0] = o;
      }
    }
  }
}

// fused spmm-2 + gather: one 64-lane wave per output row, lane = dim.
__global__ void __launch_bounds__(256) k_spmm2g(const int* __restrict__ cnt,
    const int2* __restrict__ csr, const float* __restrict__ x2,
    const float* __restrict__ all_embed, const float* __restrict__ collab1,
    const int* __restrict__ user_ids, const int* __restrict__ item_ids,
    float* __restrict__ user_e, float* __restrict__ item_e){
  int lane = threadIdx.x & 63;
  int g = (blockIdx.x*256 + threadIdx.x) >> 6;
  if (g >= 3072) return;
  int id;
  float b1;
  if (g < 1024){
    id = user_ids[g];                            // >= N_ENT
    b1 = x2[(size_t)id*64 + lane];               // users1 lives in x2
  } else {
    id = item_ids[g - 1024];
    b1 = collab1[(size_t)id*64 + lane];
  }
  float acc = all_embed[(size_t)id*64 + lane] + b1;
  int deg = cnt[id]; if (deg > RSTR) deg = RSTR;
  size_t base0 = (size_t)id << 6;
  int2 e = make_int2(0, 0);
  if (lane < deg) e = csr[base0 + lane];
  #pragma unroll 4
  for (int j = 0; j < deg; ++j){
    int cj = __shfl(e.x, j, 64);
    float vj = __int_as_float(__shfl(e.y, j, 64));
    acc += vj * x2[(size_t)cj*64 + lane];
  }
  if (g < 1024) user_e[(size_t)g*64 + lane] = acc;
  else item_e[(size_t)(g - 1024)*64 + lane] = acc;
}

// out[1024][2048] = user_e @ item_e^T, 64x64 tiles, 4x4 micro-tile, K=64
__global__ void __launch_bounds__(256) k_out(const float* __restrict__ ue,
    const float* __restrict__ ie, float* __restrict__ out){
  __shared__ float ash[64][65];
  __shared__ float bsh[64][65];
  int row0 = blockIdx.y * 64, col0 = blockIdx.x * 64;
  for (int i = threadIdx.x; i < 64*64; i += 256){
    int r = i >> 6, c = i & 63;
    ash[r][c] = ue[(size_t)(row0 + r)*DIM + c];
    bsh[r][c] = ie[(size_t)(col0 + r)*DIM + c];
  }
  __syncthreads();
  int tx = threadIdx.x & 15, ty = threadIdx.x >> 4;
  int r0 = ty*4, c0 = tx*4;
  float acc[4][4] = {};
  #pragma unroll
  for (int k = 0; k < 64; ++k){
    float a0 = ash[r0][k], a1 = ash[r0+1][k], a2 = ash[r0+2][k], a3 = ash[r0+3][k];
    float b0 = bsh[c0][k], b1 = bsh[c0+1][k], b2 = bsh[c0+2][k], b3 = bsh[c0+3][k];
    acc[0][0] += a0*b0; acc[0][1] += a0*b1; acc[0][2] += a0*b2; acc[0][3] += a0*b3;
    acc[1][0] += a1*b0; acc[1][1] += a1*b1; acc[1][2] += a1*b2; acc[1][3] += a1*b3;
    acc[2][0] += a2*b0; acc[2][1] += a2*b1; acc[2][2] += a2*b2; acc[2][3] += a2*b3;
    acc[3][0] += a3*b0; acc[3][1] += a3*b1; acc[3][2] += a3*b2; acc[3][3] += a3*b3;
  }
  #pragma unroll
  for (int i = 0; i < 4; ++i){
    float4 o = {acc[i][0], acc[i][1], acc[i][2], acc[i][3]};
    *(float4*)&out[(size_t)(row0 + r0 + i)*2048 + col0 + c0] = o;
  }
}

extern "C" void kernel_launch(void* const* d_in, const int* in_sizes, int n_in,
                              void* d_out, int out_size, void* d_ws, size_t ws_size,
                              hipStream_t stream){
  const float* all_embed = (const float*)d_in[0];
  const float* rel_embed = (const float*)d_in[1];
  const float* Wk_w      = (const float*)d_in[2];
  const float* Wk_b      = (const float*)d_in[3];
  const float* Wa_w      = (const float*)d_in[4];
  const float* Wb_w      = (const float*)d_in[5];
  const float* a_vals    = (const float*)d_in[6];
  const int* user_ids   = (const int*)d_in[7];
  const int* item_ids   = (const int*)d_in[8];
  const int* h_list     = (const int*)d_in[9];
  const int* t_list     = (const int*)d_in[10];
  const int* r_list     = (const int*)d_in[11];
  const int* a_row      = (const int*)d_in[12];
  const int* a_col      = (const int*)d_in[13];
  float* out = (float*)d_out;

  char* p = (char*)d_ws;
  auto alloc = [&](size_t bytes)->void*{
    void* r = (void*)p;
    p += (bytes + 255) & ~(size_t)255;
    return r;
  };
  float* m_rel   = (float*)alloc((size_t)N_RELC*128*4);
  float* b_rel   = (float*)alloc((size_t)N_RELC*4);
  int*   kg_off  = (int*)  alloc((size_t)(N_ENT+1)*4);
  // zero region (separate memset BEFORE k_prep — do not fuse, see R11 race)
  size_t zbytes = (size_t)N_TOTN*4 + 256 + (2*(size_t)N_ENT + 2*(size_t)N_USR);
  char*  zbase  = (char*)alloc(zbytes);
  int*   cnt      = (int*)zbase;
  int*   counters = (int*)(zbase + (size_t)N_TOTN*4);   // [0]=gate n, [1]=s1 n
  u8*    r2_item  = (u8*)(zbase + (size_t)N_TOTN*4 + 256);
  u8*    r2_user  = r2_item + N_ENT;
  u8*    need_d   = r2_user + N_USR;
  u8*    need_u   = need_d + N_ENT;
  int2*  csr     = (int2*) alloc((size_t)N_TOTN*RSTR*8);
  int*   list_gate = (int*)alloc((size_t)N_ENT*4);
  int*   list_s1   = (int*)alloc((size_t)N_TOTN*4);
  float* kg1     = (float*)alloc((size_t)N_ENT*DIM*4);
  float* collab1 = (float*)alloc((size_t)N_ENT*DIM*4);
  float* x2      = (float*)alloc((size_t)N_TOTN*DIM*4);  // [dual ; users1]
  float* user_e  = (float*)alloc((size_t)1024*DIM*4);
  float* item_e  = (float*)alloc((size_t)2048*DIM*4);

  hipMemsetAsync(zbase, 0, zbytes, stream);
  k_prep<<<29 + KGOFF_NB, 256, 0, stream>>>(rel_embed, Wk_w, Wk_b,
      m_rel, b_rel, user_ids, item_ids, r2_item, r2_user, h_list, kg_off);
  k_mark<<<MARK_NB, 256, 0, stream>>>((const int4*)a_row, (const int4*)a_col,
      r2_item, r2_user, need_d, need_u);
  k_buildfill<<<CPT_NB + FILL_NB, 256, 0, stream>>>(a_row, a_col, a_vals,
      need_d, need_u, r2_item, r2_user, list_gate, list_s1, counters, cnt, csr);
  // after k_buildfill: cnt[r] == deg(r) for needed rows, csr row r at [r*64, r*64+deg)

  k_l1<<<ATT_NB + 2048, 256, 0, stream>>>((const float4*)all_embed,
      (const float4*)m_rel, b_rel, kg_off, t_list, r_list, list_gate, list_s1,
      counters, (float4*)kg1, cnt, csr, (float4*)collab1, (float4*)x2);
  k_gate<<<256, 256, 0, stream>>>(kg1, collab1, Wa_w, Wb_w, x2,
      list_gate, counters);
  k_spmm2g<<<768, 256, 0, stream>>>(cnt, csr, x2, all_embed, collab1,
      user_ids, item_ids, user_e, item_e);
  dim3 grid_out(2048/64, 1024/64);
  k_out<<<grid_out, 256, 0, stream>>>(user_e, item_e, out);
}